// Round 2
// baseline (252.978 us; speedup 1.0000x reference)
//
#include <hip/hip_runtime.h>
#include <stdint.h>

#define LOG_N 12
#define N 4096
#define NPAIR 2048
#define ROWS 4
#define NT 512

// LDS bank-deconflict swizzle: bijection on [0,4096); <=2-way bank aliasing
// (free, m136) for all 4 ownership patterns (contig, stride-8, -64, -512).
__device__ __forceinline__ int swz(int e){
  return e ^ (((e>>6)&7)<<3) ^ (((e>>3)&1)<<2);
}

// One radix-8 phase = 3 butterfly stages on the 8 register-resident elements.
// Element k of each row sits at global position base + (k << LS0).
// increasing_stride=True and nblocks=1 -> stage index == log_stride = LS0+sub.
template<int LS0>
__device__ __forceinline__ void phase3(float (&v)[ROWS][8], int base,
                                       const float4* __restrict__ twq4){
#pragma unroll
  for(int sub=0; sub<3; ++sub){
    const int ls = LS0 + sub;
    const float4* __restrict__ twq = twq4 + ls*NPAIR;
#pragma unroll
    for(int m=0;m<4;++m){
      const int k0 = (sub==0) ? (2*m) : (sub==1) ? (((m>>1)<<2)|(m&1)) : m;
      const int k1 = k0 + (1<<sub);
      const int pos0 = base + (k0<<LS0);
      // pair index p = (pos0 >> (ls+1)) * stride + (pos0 & (stride-1))
      const int p = ((pos0>>(ls+1))<<ls) | (pos0 & ((1<<ls)-1));
      const float4 q = twq[p];          // [t00 t01 t10 t11], out_i = sum_k t[i][k]*x[k]
#pragma unroll
      for(int r=0;r<ROWS;++r){
        const float x0=v[r][k0], x1=v[r][k1];
        v[r][k0] = fmaf(q.x,x0,q.y*x1);
        v[r][k1] = fmaf(q.z,x0,q.w*x1);
      }
    }
  }
}

__global__ __launch_bounds__(NT, 4)
void butterfly_k(const float* __restrict__ x, const float* __restrict__ tw,
                 float* __restrict__ out)
{
  __shared__ float lds[ROWS*N];           // 64 KB -> 2 blocks/CU
  const int t = threadIdx.x;
  const size_t row0 = (size_t)blockIdx.x * ROWS;
  const float4* twq4 = (const float4*)tw;

  float v[ROWS][8];

  // ---- global load, phase-A ownership: e = 8t + k (2 x dwordx4 per row)
  {
    const float4* px = (const float4*)x;
#pragma unroll
    for(int r=0;r<ROWS;++r){
      const float4 a = px[(row0+r)*(N/4) + 2*t];
      const float4 b = px[(row0+r)*(N/4) + 2*t + 1];
      v[r][0]=a.x; v[r][1]=a.y; v[r][2]=a.z; v[r][3]=a.w;
      v[r][4]=b.x; v[r][5]=b.y; v[r][6]=b.z; v[r][7]=b.w;
    }
  }

  phase3<0>(v, 8*t, twq4);                // stages 0,1,2 (strides 1,2,4)

  // ---- exchange A -> B. Under swz, thread t's 8 elements stay one 8-word
  // block: base B, inner slot k ^ flip  ->  two contiguous float4 writes.
  {
    const int B = (8*t) ^ (((t>>3)&7)<<3);
    const int flip = (t&1)<<2;
#pragma unroll
    for(int r=0;r<ROWS;++r){
      float* L = lds + r*N;
      *(float4*)(L + B + flip)     = make_float4(v[r][0],v[r][1],v[r][2],v[r][3]);
      *(float4*)(L + B + (4^flip)) = make_float4(v[r][4],v[r][5],v[r][6],v[r][7]);
    }
  }
  __syncthreads();
  const int baseB = ((t>>3)<<6) | (t&7);  // e = 64*(t>>3) + (t&7) + 8k
#pragma unroll
  for(int k=0;k<8;++k){
    const int a = swz(baseB + (k<<3));
#pragma unroll
    for(int r=0;r<ROWS;++r) v[r][k] = lds[r*N + a];
  }

  phase3<3>(v, baseB, twq4);              // stages 3,4,5 (strides 8,16,32)

  // ---- exchange B -> C (thread rewrites exactly the addresses it read:
  // no barrier needed before the writes)
#pragma unroll
  for(int k=0;k<8;++k){
    const int a = swz(baseB + (k<<3));
#pragma unroll
    for(int r=0;r<ROWS;++r) lds[r*N + a] = v[r][k];
  }
  __syncthreads();
  const int baseC = ((t>>6)<<9) | (t&63); // e = 512*(t>>6) + (t&63) + 64k
#pragma unroll
  for(int k=0;k<8;++k){
    const int a = swz(baseC + (k<<6));
#pragma unroll
    for(int r=0;r<ROWS;++r) v[r][k] = lds[r*N + a];
  }

  phase3<6>(v, baseC, twq4);              // stages 6,7,8 (strides 64,128,256)

  // ---- exchange C -> D
#pragma unroll
  for(int k=0;k<8;++k){
    const int a = swz(baseC + (k<<6));
#pragma unroll
    for(int r=0;r<ROWS;++r) lds[r*N + a] = v[r][k];
  }
  __syncthreads();
  // e = t + 512k
#pragma unroll
  for(int k=0;k<8;++k){
    const int a = swz(t + (k<<9));
#pragma unroll
    for(int r=0;r<ROWS;++r) v[r][k] = lds[r*N + a];
  }

  phase3<9>(v, t, twq4);                  // stages 9,10,11 (strides 512,1024,2048)

  // ---- store: element t + 512k of each row; lanes consecutive -> coalesced
#pragma unroll
  for(int r=0;r<ROWS;++r){
    float* po = out + (row0+r)*N + t;
#pragma unroll
    for(int k=0;k<8;++k) po[(size_t)(k<<9)] = v[r][k];
  }
}

extern "C" void kernel_launch(void* const* d_in, const int* in_sizes, int n_in,
                              void* d_out, int out_size, void* d_ws, size_t ws_size,
                              hipStream_t stream) {
  const float* x  = (const float*)d_in[0];   // (8192, 4096) fp32
  const float* tw = (const float*)d_in[1];   // (1,1,12,2048,2,2) fp32
  float* out = (float*)d_out;                // (8192, 4096) fp32
  const int batch = in_sizes[0] / N;         // 8192
  dim3 grid(batch / ROWS), block(NT);
  hipLaunchKernelGGL(butterfly_k, grid, block, 0, stream, x, tw, out);
}